// Round 1
// 1061.326 us; speedup vs baseline: 1.0219x; 1.0219x over previous
//
#include <hip/hip_runtime.h>

#define N_NODES 50000
#define D_DIM   256
#define N_BATCH 4
#define M_TOTAL (N_BATCH * N_NODES)

typedef __attribute__((ext_vector_type(8))) short bf16x8;  // 8 bf16 = 4 VGPRs
typedef __attribute__((ext_vector_type(4))) float f32x4;

// ---------------- small helpers ----------------
__device__ inline float4 fma4(float a, float4 b, float4 c) {
    c.x = fmaf(a, b.x, c.x);
    c.y = fmaf(a, b.y, c.y);
    c.z = fmaf(a, b.z, c.z);
    c.w = fmaf(a, b.w, c.w);
    return c;
}

__device__ inline unsigned short f2bf(float f) {  // round-nearest-even fp32->bf16
    unsigned u = __float_as_uint(f);
    u = (u + 0x7fffu + ((u >> 16) & 1u)) >> 16;
    return (unsigned short)u;
}

__device__ inline float4 bf4tof4(ushort4 v) {
    return make_float4(__uint_as_float((unsigned)v.x << 16),
                       __uint_as_float((unsigned)v.y << 16),
                       __uint_as_float((unsigned)v.z << 16),
                       __uint_as_float((unsigned)v.w << 16));
}

// nontemporal load of one CSR edge (int2 as 64-bit scalar; little-endian: .x = low)
__device__ inline int2 nt_edge(const int2* p) {
    long long raw = __builtin_nontemporal_load((const long long*)p);
    int2 r;
    r.x = (int)(unsigned long long)raw;
    r.y = (int)((unsigned long long)raw >> 32);
    return r;
}

// async global->LDS, 16B per lane; lds dest = uniform base + lane*16
__device__ inline void async_copy16(const unsigned short* g, unsigned short* l) {
    __builtin_amdgcn_global_load_lds(
        (const __attribute__((address_space(1))) char*)g,
        (__attribute__((address_space(3))) char*)l, 16, 0, 0);
}

// ---------------- CSR build ----------------
__global__ void zero_kernel(int* __restrict__ p, int n) {
    int i = blockIdx.x * 256 + threadIdx.x;
    if (i < n) p[i] = 0;
}

__global__ void hist_kernel(const int* __restrict__ rows, int* __restrict__ counts, int E) {
    int e = blockIdx.x * 256 + threadIdx.x;
    if (e < E) atomicAdd(&counts[rows[e]], 1);
}

// Single-block exclusive scan over counts[n] -> starts[n+1], cursor[n].
__global__ void scan_kernel(const int* __restrict__ counts, int* __restrict__ starts,
                            int* __restrict__ cursor, int n) {
    __shared__ int wsum[16];
    __shared__ int btot;
    const int tid  = threadIdx.x;      // 0..1023
    const int lane = tid & 63;
    const int wid  = tid >> 6;         // 0..15
    int carry = 0;
    for (int base = 0; base < n; base += 1024) {
        int i = base + tid;
        int v = (i < n) ? counts[i] : 0;
        int x = v;
        #pragma unroll
        for (int s = 1; s < 64; s <<= 1) {
            int y = __shfl_up(x, s, 64);
            if (lane >= s) x += y;
        }
        if (lane == 63) wsum[wid] = x;
        __syncthreads();
        if (wid == 0 && lane < 16) {
            int w  = wsum[lane];
            int xx = w;
            #pragma unroll
            for (int s = 1; s < 16; s <<= 1) {
                int y = __shfl_up(xx, s, 64);
                if (lane >= s) xx += y;
            }
            wsum[lane] = xx - w;
            if (lane == 15) btot = xx;
        }
        __syncthreads();
        int excl = carry + wsum[wid] + x - v;
        if (i < n) { starts[i] = excl; cursor[i] = excl; }
        carry += btot;
        __syncthreads();
    }
    if (tid == 0) starts[n] = carry;
}

__global__ void scatter_kernel(const int* __restrict__ rows, const int* __restrict__ cols,
                               const float* __restrict__ vals, int* __restrict__ cursor,
                               int2* __restrict__ csr, int E) {
    int e = blockIdx.x * 256 + threadIdx.x;
    if (e < E) {
        int r   = rows[e];
        int pos = atomicAdd(&cursor[r], 1);
        csr[pos] = make_int2(cols[e], __float_as_int(vals[e]));
    }
}

// ---------------- casts ----------------
__global__ void cast_x_kernel(const float4* __restrict__ X, ushort4* __restrict__ Xb, int n4) {
    int i = blockIdx.x * 256 + threadIdx.x;
    if (i < n4) {
        // X is read exactly once -> nontemporal so it doesn't evict useful L3 lines
        f32x4 v = __builtin_nontemporal_load((const f32x4*)&X[i]);
        ushort4 o;
        o.x = f2bf(v.x); o.y = f2bf(v.y); o.z = f2bf(v.z); o.w = f2bf(v.w);
        Xb[i] = o;   // normal store: GEMM reads Xb right after -> keep L3-resident
    }
}

// Wt[n][k] = W[k][n], bf16
__global__ void cast_wt_kernel(const float* __restrict__ W, unsigned short* __restrict__ Wt) {
    int i = blockIdx.x * 256 + threadIdx.x;   // 65536 total
    int n = i >> 8, k = i & 255;
    Wt[n * 256 + k] = f2bf(W[k * 256 + n]);
}

// ---------------- MFMA GEMM: sup[node][batch][256] (bf16) = Xb[M,256] @ W ----------------
// 128x128 tile, 4 waves in 2x2, each wave 4x4 of 16x16x32 MFMA tiles, BK=32.
// Operands swapped (mfma(B,A,acc)) so D[row=n][col=m]: each lane stores 4 consecutive
// output cols (ushort4, 8B) at one output row -> coalesced-ish epilogue.
__global__ __launch_bounds__(256) void gemm_mfma_kernel(const unsigned short* __restrict__ Xb,
                                                        const unsigned short* __restrict__ Wt,
                                                        unsigned short* __restrict__ sup) {
    __shared__ unsigned short at[128 * 32];   // [row][k], row stride 64B
    __shared__ unsigned short bt[128 * 32];   // [n][k]
    const int tid  = threadIdx.x;
    const int lane = tid & 63;
    const int wid  = tid >> 6;
    const int wm   = wid & 1, wn = wid >> 1;
    const int row0 = (blockIdx.x >> 1) * 128;
    const int col0 = (blockIdx.x & 1) * 128;
    const int fr    = lane & 15;          // fragment row index
    const int fk    = (lane >> 4) * 8;    // fragment k offset
    const int srow  = lane >> 2;          // staging sub-row 0..15
    const int skoff = (lane & 3) * 8;     // staging k offset (ushorts)

    f32x4 acc[4][4];
    #pragma unroll
    for (int a = 0; a < 4; ++a)
        #pragma unroll
        for (int b = 0; b < 4; ++b) acc[a][b] = (f32x4){0.f, 0.f, 0.f, 0.f};

    for (int kc = 0; kc < 256; kc += 32) {
        #pragma unroll
        for (int c = 0; c < 2; ++c) {
            int r = wid * 32 + c * 16;                 // chunk base row (uniform per wave)
            int gra = row0 + r + srow; if (gra >= M_TOTAL) gra = M_TOTAL - 1;
            async_copy16(Xb + (size_t)gra * 256 + kc + skoff, &at[r * 32]);
            int grb = col0 + r + srow;
            async_copy16(Wt + (size_t)grb * 256 + kc + skoff, &bt[r * 32]);
        }
        __syncthreads();   // drains vmcnt for global_load_lds
        bf16x8 af[4], bfr[4];
        #pragma unroll
        for (int t = 0; t < 4; ++t) {
            af[t]  = *(const bf16x8*)&at[(wm * 64 + t * 16 + fr) * 32 + fk];
            bfr[t] = *(const bf16x8*)&bt[(wn * 64 + t * 16 + fr) * 32 + fk];
        }
        #pragma unroll
        for (int tn = 0; tn < 4; ++tn)
            #pragma unroll
            for (int tm = 0; tm < 4; ++tm)
                acc[tn][tm] = __builtin_amdgcn_mfma_f32_16x16x32_bf16(bfr[tn], af[tm], acc[tn][tm], 0, 0, 0);
        __syncthreads();
    }

    // epilogue: D[row=n][col=m]; lane holds output row m = ...+fr, cols n0..n0+3
    #pragma unroll
    for (int tm = 0; tm < 4; ++tm) {
        int gr = row0 + wm * 64 + tm * 16 + fr;        // flattened b*N_NODES+node
        if (gr < M_TOTAL) {
            int b    = (int)((unsigned)gr / (unsigned)N_NODES);
            int node = gr - b * N_NODES;
            size_t base = ((size_t)node * 4 + b) * 256;
            #pragma unroll
            for (int tn = 0; tn < 4; ++tn) {
                int col = col0 + wn * 64 + tn * 16 + (lane >> 4) * 4;
                ushort4 o;
                o.x = f2bf(acc[tn][tm][0]);
                o.y = f2bf(acc[tn][tm][1]);
                o.z = f2bf(acc[tn][tm][2]);
                o.w = f2bf(acc[tn][tm][3]);
                *(ushort4*)&sup[base + col] = o;   // normal store: spmm gathers this -> keep in L3
            }
        }
    }
}

// ---------------- SpMM: out[b,r,:] = sum_e val * sup[col_e][b][:] + bias ----------------
// One block per node row; wave = batch; lane owns 4 cols. Per edge one 2KB
// contiguous block read (all 4 batches). No atomics; bias fused.
// Key change this round: `out` (204.8MB) is stored NONTEMPORAL so the streaming
// writes do not write-allocate and evict `sup` (102.4MB, L3-resident) from the
// 256MB Infinity Cache; csr entries (streamed once) are nontemporal loads.
// Edge loop unrolled 8x for extra MLP once gathers become L3-latency (12 VGPRs
// of headroom -> still full occupancy).
__global__ __launch_bounds__(256) void spmm_kernel(const unsigned short* __restrict__ sup,
                                                   const int* __restrict__ starts,
                                                   const int2* __restrict__ csr,
                                                   const float* __restrict__ bias,
                                                   float* __restrict__ out) {
    const int row  = blockIdx.x;
    const int b    = threadIdx.x >> 6;
    const int lane = threadIdx.x & 63;
    const unsigned short* supb = sup + (size_t)b * 256 + (size_t)lane * 4;
    const int s = starts[row];
    const int e = starts[row + 1];
    float4 acc = make_float4(0.f, 0.f, 0.f, 0.f);
    int i = s;
    for (; i + 7 < e; i += 8) {     // unroll-8 for memory-level parallelism
        int2 ed[8];
        #pragma unroll
        for (int u = 0; u < 8; ++u) ed[u] = nt_edge(&csr[i + u]);
        ushort4 v[8];
        #pragma unroll
        for (int u = 0; u < 8; ++u) v[u] = *(const ushort4*)(supb + (size_t)ed[u].x * 1024);
        #pragma unroll
        for (int u = 0; u < 8; ++u) acc = fma4(__int_as_float(ed[u].y), bf4tof4(v[u]), acc);
    }
    for (; i + 1 < e; i += 2) {
        int2 e0 = nt_edge(&csr[i]);
        int2 e1 = nt_edge(&csr[i + 1]);
        ushort4 v0 = *(const ushort4*)(supb + (size_t)e0.x * 1024);
        ushort4 v1 = *(const ushort4*)(supb + (size_t)e1.x * 1024);
        acc = fma4(__int_as_float(e0.y), bf4tof4(v0), acc);
        acc = fma4(__int_as_float(e1.y), bf4tof4(v1), acc);
    }
    for (; i < e; ++i) {
        int2 e0 = nt_edge(&csr[i]);
        ushort4 v0 = *(const ushort4*)(supb + (size_t)e0.x * 1024);
        acc = fma4(__int_as_float(e0.y), bf4tof4(v0), acc);
    }
    float4 bb = ((const float4*)bias)[lane];
    f32x4 o;
    o.x = acc.x + bb.x; o.y = acc.y + bb.y; o.z = acc.z + bb.z; o.w = acc.w + bb.w;
    f32x4* dst = (f32x4*)out + ((size_t)b * N_NODES + row) * (D_DIM / 4) + lane;
    __builtin_nontemporal_store(o, dst);   // don't write-allocate: protect sup in L3
}

// ---------------- launch ----------------
extern "C" void kernel_launch(void* const* d_in, const int* in_sizes, int n_in,
                              void* d_out, int out_size, void* d_ws, size_t ws_size,
                              hipStream_t stream) {
    const float* X    = (const float*)d_in[0];
    const int*   rows = (const int*)d_in[1];
    const int*   cols = (const int*)d_in[2];
    const float* vals = (const float*)d_in[3];
    const float* W    = (const float*)d_in[4];
    const float* bias = (const float*)d_in[5];
    float*       out  = (float*)d_out;
    const int E = in_sizes[1];

    char* wsb = (char*)d_ws;
    size_t o = 0;
    auto alloc = [&](size_t bytes) -> char* {
        char* p = wsb + o;
        o += (bytes + 255) & ~(size_t)255;
        return p;
    };
    int*  counts = (int*)alloc((size_t)N_NODES * 4);
    int*  starts = (int*)alloc((size_t)(N_NODES + 1) * 4);
    int*  cursor = (int*)alloc((size_t)N_NODES * 4);           // reused as Wt after scatter
    int2* csr    = (int2*)alloc((size_t)E * 8);
    unsigned short* Xb  = (unsigned short*)alloc((size_t)M_TOTAL * D_DIM * 2);   // 102.4 MB
    unsigned short* sup = (unsigned short*)alloc((size_t)N_NODES * N_BATCH * D_DIM * 2); // 102.4 MB
    unsigned short* Wt  = (unsigned short*)cursor;             // 128 KB < 200 KB cursor region

    // CSR build (graph identical across batches — build once)
    zero_kernel<<<(N_NODES + 255) / 256, 256, 0, stream>>>(counts, N_NODES);
    hist_kernel<<<(E + 255) / 256, 256, 0, stream>>>(rows, counts, E);
    scan_kernel<<<1, 1024, 0, stream>>>(counts, starts, cursor, N_NODES);
    scatter_kernel<<<(E + 255) / 256, 256, 0, stream>>>(rows, cols, vals, cursor, csr, E);

    // casts (cast_wt AFTER scatter: it overwrites cursor)
    const int n4 = M_TOTAL * D_DIM / 4;
    cast_x_kernel<<<(n4 + 255) / 256, 256, 0, stream>>>((const float4*)X, (ushort4*)Xb, n4);
    cast_wt_kernel<<<(256 * 256) / 256, 256, 0, stream>>>(W, Wt);

    // GEMM -> sup (bf16, [node][batch][256])
    const int rowTiles = (M_TOTAL + 127) / 128;
    gemm_mfma_kernel<<<rowTiles * 2, 256, 0, stream>>>(Xb, Wt, sup);

    // SpMM + bias
    spmm_kernel<<<N_NODES, 256, 0, stream>>>(sup, starts, csr, bias, out);
}

// Round 3
// 1006.634 us; speedup vs baseline: 1.0774x; 1.0543x over previous
//
#include <hip/hip_runtime.h>

#define N_NODES 50000
#define D_DIM   256
#define N_BATCH 4
#define M_TOTAL (N_BATCH * N_NODES)

typedef __attribute__((ext_vector_type(8))) short bf16x8;  // 8 bf16 = 4 VGPRs
typedef __attribute__((ext_vector_type(4))) float f32x4;

// ---------------- small helpers ----------------
__device__ inline float4 fma4(float a, float4 b, float4 c) {
    c.x = fmaf(a, b.x, c.x);
    c.y = fmaf(a, b.y, c.y);
    c.z = fmaf(a, b.z, c.z);
    c.w = fmaf(a, b.w, c.w);
    return c;
}

__device__ inline unsigned short f2bf(float f) {  // round-nearest-even fp32->bf16
    unsigned u = __float_as_uint(f);
    u = (u + 0x7fffu + ((u >> 16) & 1u)) >> 16;
    return (unsigned short)u;
}

__device__ inline float4 bf4tof4(ushort4 v) {
    return make_float4(__uint_as_float((unsigned)v.x << 16),
                       __uint_as_float((unsigned)v.y << 16),
                       __uint_as_float((unsigned)v.z << 16),
                       __uint_as_float((unsigned)v.w << 16));
}

// async global->LDS, 16B per lane; lds dest = uniform base + lane*16
__device__ inline void async_copy16(const unsigned short* g, unsigned short* l) {
    __builtin_amdgcn_global_load_lds(
        (const __attribute__((address_space(1))) char*)g,
        (__attribute__((address_space(3))) char*)l, 16, 0, 0);
}

// ---------------- init: zero counts + transpose-cast W (order-independent now) ----------------
__global__ void init_kernel(int* __restrict__ counts, const float* __restrict__ W,
                            unsigned short* __restrict__ Wt) {
    int i = blockIdx.x * 256 + threadIdx.x;   // 65536 threads
    if (i < N_NODES) counts[i] = 0;
    int n = i >> 8, k = i & 255;
    Wt[n * 256 + k] = f2bf(W[k * 256 + n]);
}

__global__ void hist_kernel(const int* __restrict__ rows, int* __restrict__ counts, int E) {
    int e = blockIdx.x * 256 + threadIdx.x;
    if (e < E) atomicAdd(&counts[rows[e]], 1);
}

// ---------------- parallel 3-phase exclusive scan ----------------
// phase 1: per-1024-block exclusive scan, emit block totals
__global__ __launch_bounds__(1024) void scan1_kernel(const int* __restrict__ counts,
                                                     int* __restrict__ starts,
                                                     int* __restrict__ bsum, int n) {
    __shared__ int wsum[16];
    __shared__ int btot;
    const int tid  = threadIdx.x;
    const int lane = tid & 63;
    const int wid  = tid >> 6;
    int i = blockIdx.x * 1024 + tid;
    int v = (i < n) ? counts[i] : 0;
    int x = v;
    #pragma unroll
    for (int s = 1; s < 64; s <<= 1) {
        int y = __shfl_up(x, s, 64);
        if (lane >= s) x += y;
    }
    if (lane == 63) wsum[wid] = x;
    __syncthreads();
    if (wid == 0 && lane < 16) {
        int w  = wsum[lane];
        int xx = w;
        #pragma unroll
        for (int s = 1; s < 16; s <<= 1) {
            int y = __shfl_up(xx, s, 64);
            if (lane >= s) xx += y;
        }
        wsum[lane] = xx - w;
        if (lane == 15) btot = xx;
    }
    __syncthreads();
    if (i < n) starts[i] = wsum[wid] + x - v;
    if (tid == 0) bsum[blockIdx.x] = btot;
}

// phase 2: single-wave exclusive scan of the <=64 block totals; writes grand total
__global__ void scan2_kernel(int* __restrict__ bsum, int* __restrict__ starts, int nb, int n) {
    int lane = threadIdx.x;          // blockDim = 64
    int v = (lane < nb) ? bsum[lane] : 0;
    int x = v;
    #pragma unroll
    for (int s = 1; s < 64; s <<= 1) {
        int y = __shfl_up(x, s, 64);
        if (lane >= s) x += y;
    }
    if (lane < nb) bsum[lane] = x - v;
    if (lane == 63) starts[n] = x;   // grand total = E
}

// phase 3: add block offsets, fill cursor
__global__ void scan3_kernel(int* __restrict__ starts, int* __restrict__ cursor,
                             const int* __restrict__ bsum, int n) {
    int i = blockIdx.x * 256 + threadIdx.x;
    if (i < n) {
        int s = starts[i] + bsum[i >> 10];
        starts[i] = s;
        cursor[i] = s;
    }
}

__global__ void scatter_kernel(const int* __restrict__ rows, const int* __restrict__ cols,
                               const float* __restrict__ vals, int* __restrict__ cursor,
                               int2* __restrict__ csr, int E) {
    int e = blockIdx.x * 256 + threadIdx.x;
    if (e < E) {
        int r   = rows[e];
        int pos = atomicAdd(&cursor[r], 1);
        csr[pos] = make_int2(cols[e], __float_as_int(vals[e]));
    }
}

// ---------------- MFMA GEMM with fused fp32->bf16 A-cast ----------------
// sup[node][batch][256] (bf16) = X[M,256](fp32) @ W
// 128x128 tile, 4 waves 2x2, BK=32. A: reg-staged from fp32 X with in-kernel
// convert (kills the separate cast_x pass + 102.4MB Xb round-trip). B: bf16 Wt
// via global_load_lds (L2-resident, 128KB).
__global__ __launch_bounds__(256) void gemm_mfma_kernel(const float* __restrict__ X,
                                                        const unsigned short* __restrict__ Wt,
                                                        unsigned short* __restrict__ sup) {
    __shared__ unsigned short at[128 * 32];   // [row][k], row stride 64B
    __shared__ unsigned short bt[128 * 32];   // [n][k]
    const int tid  = threadIdx.x;
    const int lane = tid & 63;
    const int wid  = tid >> 6;
    const int wm   = wid & 1, wn = wid >> 1;
    const int row0 = (blockIdx.x >> 1) * 128;
    const int col0 = (blockIdx.x & 1) * 128;
    const int fr    = lane & 15;          // fragment row index
    const int fk    = (lane >> 4) * 8;    // fragment k offset
    const int srow  = lane >> 2;          // staging sub-row 0..15 (B path)
    const int skoff = (lane & 3) * 8;     // staging k offset (B path)

    f32x4 acc[4][4];
    #pragma unroll
    for (int a = 0; a < 4; ++a)
        #pragma unroll
        for (int b = 0; b < 4; ++b) acc[a][b] = (f32x4){0.f, 0.f, 0.f, 0.f};

    for (int kc = 0; kc < 256; kc += 32) {
        // B staging: async bf16, 2 x 4KB
        #pragma unroll
        for (int c = 0; c < 2; ++c) {
            int r = wid * 32 + c * 16;
            int grb = col0 + r + srow;
            async_copy16(Wt + (size_t)grb * 256 + kc + skoff, &bt[r * 32]);
        }
        // A staging: load fp32, convert, ds_write. slot s covers 8 k-elems of one row.
        #pragma unroll
        for (int s0 = 0; s0 < 2; ++s0) {
            int s    = tid + s0 * 256;            // 0..511
            int arow = s >> 2;                    // 0..127
            int koff = (s & 3) * 8;               // 0,8,16,24
            int gra  = row0 + arow; if (gra >= M_TOTAL) gra = M_TOTAL - 1;
            const float* src = X + (size_t)gra * 256 + kc + koff;
            float4 v0 = *(const float4*)src;
            float4 v1 = *(const float4*)(src + 4);
            ushort4 lo, hi;
            lo.x = f2bf(v0.x); lo.y = f2bf(v0.y); lo.z = f2bf(v0.z); lo.w = f2bf(v0.w);
            hi.x = f2bf(v1.x); hi.y = f2bf(v1.y); hi.z = f2bf(v1.z); hi.w = f2bf(v1.w);
            *(ushort4*)&at[arow * 32 + koff]     = lo;
            *(ushort4*)&at[arow * 32 + koff + 4] = hi;
        }
        __syncthreads();   // drains vmcnt (B) + lgkmcnt (A ds_write)
        bf16x8 af[4], bfr[4];
        #pragma unroll
        for (int t = 0; t < 4; ++t) {
            af[t]  = *(const bf16x8*)&at[(wm * 64 + t * 16 + fr) * 32 + fk];
            bfr[t] = *(const bf16x8*)&bt[(wn * 64 + t * 16 + fr) * 32 + fk];
        }
        #pragma unroll
        for (int tn = 0; tn < 4; ++tn)
            #pragma unroll
            for (int tm = 0; tm < 4; ++tm)
                acc[tn][tm] = __builtin_amdgcn_mfma_f32_16x16x32_bf16(bfr[tn], af[tm], acc[tn][tm], 0, 0, 0);
        __syncthreads();
    }

    // epilogue: D[row=n][col=m]; lane holds output row m = ...+fr, cols n0..n0+3
    #pragma unroll
    for (int tm = 0; tm < 4; ++tm) {
        int gr = row0 + wm * 64 + tm * 16 + fr;        // flattened b*N_NODES+node
        if (gr < M_TOTAL) {
            int b    = (int)((unsigned)gr / (unsigned)N_NODES);
            int node = gr - b * N_NODES;
            size_t base = ((size_t)node * 4 + b) * 256;
            #pragma unroll
            for (int tn = 0; tn < 4; ++tn) {
                int col = col0 + wn * 64 + tn * 16 + (lane >> 4) * 4;
                ushort4 o;
                o.x = f2bf(acc[tn][tm][0]);
                o.y = f2bf(acc[tn][tm][1]);
                o.z = f2bf(acc[tn][tm][2]);
                o.w = f2bf(acc[tn][tm][3]);
                *(ushort4*)&sup[base + col] = o;
            }
        }
    }
}

// ---------------- SpMM: out[b,r,:] = sum_e val * sup[col_e][b][:] + bias ----------------
// UNCHANGED (control): pinned at ~463us / 3.87 TB/s fabric traffic.
__global__ __launch_bounds__(256) void spmm_kernel(const unsigned short* __restrict__ sup,
                                                   const int* __restrict__ starts,
                                                   const int2* __restrict__ csr,
                                                   const float* __restrict__ bias,
                                                   float* __restrict__ out) {
    const int row  = blockIdx.x;
    const int b    = threadIdx.x >> 6;
    const int lane = threadIdx.x & 63;
    const unsigned short* supb = sup + (size_t)b * 256 + (size_t)lane * 4;
    const int s = starts[row];
    const int e = starts[row + 1];
    float4 acc = make_float4(0.f, 0.f, 0.f, 0.f);
    int i = s;
    for (; i + 7 < e; i += 8) {     // unroll-8 for memory-level parallelism
        int2 ed[8];
        #pragma unroll
        for (int u = 0; u < 8; ++u) ed[u] = csr[i + u];
        ushort4 v[8];
        #pragma unroll
        for (int u = 0; u < 8; ++u) v[u] = *(const ushort4*)(supb + (size_t)ed[u].x * 1024);
        #pragma unroll
        for (int u = 0; u < 8; ++u) acc = fma4(__int_as_float(ed[u].y), bf4tof4(v[u]), acc);
    }
    for (; i + 1 < e; i += 2) {
        int2 e0 = csr[i];
        int2 e1 = csr[i + 1];
        ushort4 v0 = *(const ushort4*)(supb + (size_t)e0.x * 1024);
        ushort4 v1 = *(const ushort4*)(supb + (size_t)e1.x * 1024);
        acc = fma4(__int_as_float(e0.y), bf4tof4(v0), acc);
        acc = fma4(__int_as_float(e1.y), bf4tof4(v1), acc);
    }
    for (; i < e; ++i) {
        int2 e0 = csr[i];
        ushort4 v0 = *(const ushort4*)(supb + (size_t)e0.x * 1024);
        acc = fma4(__int_as_float(e0.y), bf4tof4(v0), acc);
    }
    float4 bb = ((const float4*)bias)[lane];
    f32x4 o;
    o.x = acc.x + bb.x; o.y = acc.y + bb.y; o.z = acc.z + bb.z; o.w = acc.w + bb.w;
    f32x4* dst = (f32x4*)out + ((size_t)b * N_NODES + row) * (D_DIM / 4) + lane;
    __builtin_nontemporal_store(o, dst);
}

// ---------------- launch ----------------
extern "C" void kernel_launch(void* const* d_in, const int* in_sizes, int n_in,
                              void* d_out, int out_size, void* d_ws, size_t ws_size,
                              hipStream_t stream) {
    const float* X    = (const float*)d_in[0];
    const int*   rows = (const int*)d_in[1];
    const int*   cols = (const int*)d_in[2];
    const float* vals = (const float*)d_in[3];
    const float* W    = (const float*)d_in[4];
    const float* bias = (const float*)d_in[5];
    float*       out  = (float*)d_out;
    const int E = in_sizes[1];

    char* wsb = (char*)d_ws;
    size_t o = 0;
    auto alloc = [&](size_t bytes) -> char* {
        char* p = wsb + o;
        o += (bytes + 255) & ~(size_t)255;
        return p;
    };
    int*  counts = (int*)alloc((size_t)N_NODES * 4);
    int*  starts = (int*)alloc((size_t)(N_NODES + 1) * 4);
    int*  cursor = (int*)alloc((size_t)N_NODES * 4);
    int*  bsum   = (int*)alloc(64 * 4);
    unsigned short* Wt = (unsigned short*)alloc((size_t)256 * 256 * 2);          // 128 KB
    int2* csr    = (int2*)alloc((size_t)E * 8);
    unsigned short* sup = (unsigned short*)alloc((size_t)N_NODES * N_BATCH * D_DIM * 2); // 102.4 MB

    const int NB = (N_NODES + 1023) / 1024;   // 49 scan blocks

    // init (zero counts + Wt transpose-cast, order-independent)
    init_kernel<<<256, 256, 0, stream>>>(counts, W, Wt);
    hist_kernel<<<(E + 255) / 256, 256, 0, stream>>>(rows, counts, E);

    // parallel scan: starts/cursor
    scan1_kernel<<<NB, 1024, 0, stream>>>(counts, starts, bsum, N_NODES);
    scan2_kernel<<<1, 64, 0, stream>>>(bsum, starts, NB, N_NODES);
    scan3_kernel<<<(N_NODES + 255) / 256, 256, 0, stream>>>(starts, cursor, bsum, N_NODES);

    scatter_kernel<<<(E + 255) / 256, 256, 0, stream>>>(rows, cols, vals, cursor, csr, E);

    // fused cast+GEMM -> sup (bf16, [node][batch][256])
    const int rowTiles = (M_TOTAL + 127) / 128;
    gemm_mfma_kernel<<<rowTiles * 2, 256, 0, stream>>>(X, Wt, sup);

    // SpMM + bias
    spmm_kernel<<<N_NODES, 256, 0, stream>>>(sup, starts, csr, bias, out);
}